// Round 1
// baseline (630.111 us; speedup 1.0000x reference)
//
#include <hip/hip_runtime.h>
#include <math.h>

// ---------------------------------------------------------------------------
// Types / helpers
// ---------------------------------------------------------------------------
using u16 = unsigned short;
typedef __attribute__((ext_vector_type(8))) short short8;   // 8 x bf16 (as raw bits)
typedef __attribute__((ext_vector_type(4))) float f32x4;
typedef __attribute__((ext_vector_type(4))) u16 u16x4;

#define DEV __device__ __forceinline__

DEV u16 f2bf(float f) {                       // f32 -> bf16, round-nearest-even
    unsigned u = __float_as_uint(f);
    u += 0x7fffu + ((u >> 16) & 1u);
    return (u16)(u >> 16);
}
DEV float bf2f(u16 h) { return __uint_as_float(((unsigned)h) << 16); }

DEV short8 ld16(const u16* p) { return *reinterpret_cast<const short8*>(p); }

DEV float gelu_f(float x) { return 0.5f * x * (1.f + erff(x * 0.70710678118654752f)); }

// async global->LDS, 16B per lane, LDS dest = wave-uniform base + lane*16
#define GLL16(gp, lp)                                                          \
    __builtin_amdgcn_global_load_lds(                                          \
        (const __attribute__((address_space(1))) void*)(gp),                   \
        (__attribute__((address_space(3))) void*)(lp), 16, 0, 0)

// ---------------------------------------------------------------------------
// fp32 -> bf16 convert (weights)
// ---------------------------------------------------------------------------
__global__ void cvt_f32_bf16(const float* __restrict__ in, u16* __restrict__ out, int n4) {
    int i = blockIdx.x * 256 + threadIdx.x;
    if (i >= n4) return;
    float4 v = reinterpret_cast<const float4*>(in)[i];
    u16x4 o;
    o.x = f2bf(v.x); o.y = f2bf(v.y); o.z = f2bf(v.z); o.w = f2bf(v.w);
    reinterpret_cast<u16x4*>(out)[i] = o;
}

// ---------------------------------------------------------------------------
// LayerNorm (fp32 in) -> bf16 out.  One block per row, 256 threads x 4 floats.
// ---------------------------------------------------------------------------
__global__ __launch_bounds__(256) void ln_bf16(const float* __restrict__ x,
                                               const float* __restrict__ gm,
                                               const float* __restrict__ bt,
                                               u16* __restrict__ out) {
    const int row = blockIdx.x, tid = threadIdx.x;
    const float4 v = reinterpret_cast<const float4*>(x + (long)row * 1024)[tid];
    float s  = v.x + v.y + v.z + v.w;
    float sq = v.x * v.x + v.y * v.y + v.z * v.z + v.w * v.w;
#pragma unroll
    for (int off = 1; off <= 32; off <<= 1) {
        s  += __shfl_xor(s, off);
        sq += __shfl_xor(sq, off);
    }
    __shared__ float ss[4], ssq[4];
    const int wave = tid >> 6, lane = tid & 63;
    if (lane == 0) { ss[wave] = s; ssq[wave] = sq; }
    __syncthreads();
    s  = ss[0] + ss[1] + ss[2] + ss[3];
    sq = ssq[0] + ssq[1] + ssq[2] + ssq[3];
    const float mu   = s * (1.f / 1024.f);
    const float var  = sq * (1.f / 1024.f) - mu * mu;
    const float rstd = rsqrtf(var + 1e-5f);
    const float4 g4 = reinterpret_cast<const float4*>(gm)[tid];
    const float4 b4 = reinterpret_cast<const float4*>(bt)[tid];
    u16x4 o;
    o.x = f2bf((v.x - mu) * rstd * g4.x + b4.x);
    o.y = f2bf((v.y - mu) * rstd * g4.y + b4.y);
    o.z = f2bf((v.z - mu) * rstd * g4.z + b4.z);
    o.w = f2bf((v.w - mu) * rstd * g4.w + b4.w);
    reinterpret_cast<u16x4*>(out + (long)row * 1024)[tid] = o;
}

// ---------------------------------------------------------------------------
// GEMM: C[M,N] = A[M,K] @ B[N,K]^T + bias.  A,B bf16; 128x128 tile, BK=32,
// 4 waves (2x2), 4x4 16x16x32 MFMA frags per wave, global_load_lds staging.
// EPI: 0 = bf16 out, 1 = bf16 gelu out, 2 = fp32 out + residual,
//      3 = scatter into Q [BH,S,64], K [BH,S,64], Vt [BH,64,S]
// ---------------------------------------------------------------------------
template <int EPI>
__global__ __launch_bounds__(256, 2) void gemm_bt(
    const u16* __restrict__ A, const u16* __restrict__ B,
    const float* __restrict__ bias, const float* res, float* outf,
    u16* __restrict__ outb, u16* __restrict__ Qb, u16* __restrict__ Kb,
    u16* __restrict__ Vtb, int M, int N, int K) {
    __shared__ u16 As[128 * 32];
    __shared__ u16 Bs[128 * 32];
    const int tid = threadIdx.x;
    const int wave = tid >> 6, lane = tid & 63;
    const int row0 = blockIdx.y * 128, col0 = blockIdx.x * 128;
    const int wr = wave >> 1, wc = wave & 1;
    const int lo = lane & 15, g = lane >> 4;

    // staging addresses: wave handles chunks {wave, wave+4} (1024B each)
    const u16* Ag = A + (long)(row0 + wave * 16 + (lane >> 2)) * K + (lane & 3) * 8;
    const u16* Bg = B + (long)(col0 + wave * 16 + (lane >> 2)) * K + (lane & 3) * 8;
    u16* Al = As + wave * 512;
    u16* Bl = Bs + wave * 512;

    f32x4 acc[4][4] = {};

    for (int k0 = 0; k0 < K; k0 += 32) {
        GLL16(Ag, Al);
        GLL16(Ag + 64 * (long)K, Al + 2048);
        GLL16(Bg, Bl);
        GLL16(Bg + 64 * (long)K, Bl + 2048);
        Ag += 32; Bg += 32;
        __syncthreads();           // staging complete (vmcnt drained at barrier)
        short8 af[4], bf[4];
#pragma unroll
        for (int m = 0; m < 4; ++m)
            af[m] = ld16(&As[(wr * 64 + m * 16 + lo) * 32 + g * 8]);
#pragma unroll
        for (int n = 0; n < 4; ++n)
            bf[n] = ld16(&Bs[(wc * 64 + n * 16 + lo) * 32 + g * 8]);
#pragma unroll
        for (int m = 0; m < 4; ++m)
#pragma unroll
            for (int n = 0; n < 4; ++n)
                acc[m][n] = __builtin_amdgcn_mfma_f32_16x16x32_bf16(
                    af[m], bf[n], acc[m][n], 0, 0, 0);
        __syncthreads();           // compute done before next-tile overwrite
    }

    // epilogue: D layout (16x16x32): col = lane&15, row = (lane>>4)*4 + j
#pragma unroll
    for (int m = 0; m < 4; ++m) {
#pragma unroll
        for (int n = 0; n < 4; ++n) {
            const int c = col0 + wc * 64 + n * 16 + lo;
            const float bs = bias[c];
#pragma unroll
            for (int j = 0; j < 4; ++j) {
                const int r = row0 + wr * 64 + m * 16 + g * 4 + j;
                const float val = acc[m][n][j] + bs;
                if constexpr (EPI == 0) {
                    outb[(long)r * N + c] = f2bf(val);
                } else if constexpr (EPI == 1) {
                    outb[(long)r * N + c] = f2bf(gelu_f(val));
                } else if constexpr (EPI == 2) {
                    outf[(long)r * N + c] = res[(long)r * N + c] + val;
                } else {  // EPI == 3: qkv scatter
                    const int part = c >> 10, cc = c & 1023;
                    const int head = cc >> 6, d = cc & 63;
                    const int bb = r >> 11, srow = r & 2047;
                    const int bh = bb * 16 + head;
                    const u16 hv = f2bf(val);
                    if (part == 0)      Qb[((long)bh * 2048 + srow) * 64 + d] = hv;
                    else if (part == 1) Kb[((long)bh * 2048 + srow) * 64 + d] = hv;
                    else                Vtb[((long)bh * 64 + d) * 2048 + srow] = hv;
                }
            }
        }
    }
}

// ---------------------------------------------------------------------------
// Causal flash attention.  Q,K: [BH, S, 64] bf16.  Vt: [BH, 64, S] bf16.
// O: [B, S, H*64] bf16.  One wave = 16 q rows; block = 4 waves = 64 q rows.
// Computes S^T = K*Q^T (softmax rows land on lane columns) and O^T = Vt*P^T.
// ---------------------------------------------------------------------------
__global__ __launch_bounds__(256, 2) void attn_fwd(
    const u16* __restrict__ Q, const u16* __restrict__ K,
    const u16* __restrict__ Vt, u16* __restrict__ O) {
    const int bh = blockIdx.x, qt = blockIdx.y;
    const int wave = threadIdx.x >> 6, lane = threadIdx.x & 63;
    const int lo = lane & 15, g = lane >> 4;
    const int qw = qt * 64 + wave * 16;

    const u16* Qp = Q + ((long)bh * 2048 + qw) * 64;
    const u16* Kp = K + (long)bh * 2048 * 64;
    const u16* Vp = Vt + (long)bh * 64 * 2048;

    // Q B-frag: lane holds Q[qw+lo][hc*32 + g*8 + jj]
    const short8 qf0 = ld16(Qp + lo * 64 + g * 8);
    const short8 qf1 = ld16(Qp + lo * 64 + 32 + g * 8);

    float m = -1e30f, lsum = 0.f;
    f32x4 oa[4] = {};
    const float scale = 0.125f;  // 1/sqrt(64)
    const int q_abs = qw + lo;
    const int kv_end = qw + 16;

    for (int kv0 = 0; kv0 < kv_end; kv0 += 32) {
        // K A-frags (two kv halves x two hd chunks)
        const u16* Krow = Kp + (long)(kv0 + lo) * 64 + g * 8;
        const short8 k00 = ld16(Krow);
        const short8 k01 = ld16(Krow + 32);
        const short8 k10 = ld16(Krow + 16 * 64);
        const short8 k11 = ld16(Krow + 16 * 64 + 32);
        f32x4 s0 = {}, s1 = {};
        s0 = __builtin_amdgcn_mfma_f32_16x16x32_bf16(k00, qf0, s0, 0, 0, 0);
        s0 = __builtin_amdgcn_mfma_f32_16x16x32_bf16(k01, qf1, s0, 0, 0, 0);
        s1 = __builtin_amdgcn_mfma_f32_16x16x32_bf16(k10, qf0, s1, 0, 0, 0);
        s1 = __builtin_amdgcn_mfma_f32_16x16x32_bf16(k11, qf1, s1, 0, 0, 0);

        // scale + causal mask; lane holds S^T[kv=kv0+half*16+g*4+j][q=lo]
        float p[8];
        float mt = -1e30f;
#pragma unroll
        for (int j = 0; j < 4; ++j) {
            int kv = kv0 + g * 4 + j;
            float v = s0[j] * scale;
            if (kv > q_abs) v = -1e30f;
            p[j] = v; mt = fmaxf(mt, v);
            kv = kv0 + 16 + g * 4 + j;
            v = s1[j] * scale;
            if (kv > q_abs) v = -1e30f;
            p[4 + j] = v; mt = fmaxf(mt, v);
        }
        // row max across the 4 g-groups holding this q column
        mt = fmaxf(mt, __shfl_xor(mt, 16));
        mt = fmaxf(mt, __shfl_xor(mt, 32));
        const float mn = fmaxf(m, mt);
        const float corr = __expf(m - mn);
        m = mn;
        lsum *= corr;
#pragma unroll
        for (int c = 0; c < 4; ++c) oa[c] *= corr;
        float psum = 0.f;
#pragma unroll
        for (int i = 0; i < 8; ++i) { p[i] = __expf(p[i] - mn); psum += p[i]; }
        lsum += psum;

        // transpose P into B-frag: lane needs P[q=lo][kv = kv0 + g*8 + jj]
        short8 pb;
#pragma unroll
        for (int jj = 0; jj < 8; ++jj) {
            const int src = lo + 16 * ((g & 1) * 2 + (jj >> 2));
            const float v0 = __shfl(p[jj & 3], src);
            const float v1 = __shfl(p[4 + (jj & 3)], src);
            pb[jj] = (short)f2bf((g >> 1) ? v1 : v0);
        }
        // O^T += Vt-frag * P^T   (4 hd chunks of 16)
#pragma unroll
        for (int c = 0; c < 4; ++c) {
            const short8 vf = ld16(Vp + (long)(c * 16 + lo) * 2048 + kv0 + g * 8);
            oa[c] = __builtin_amdgcn_mfma_f32_16x16x32_bf16(vf, pb, oa[c], 0, 0, 0);
        }
    }
    // finish: row sum across g-groups, normalize, store
    lsum += __shfl_xor(lsum, 16);
    lsum += __shfl_xor(lsum, 32);
    const float inv = 1.f / lsum;
    const int bb = bh >> 4, h = bh & 15;
    u16* Orow = O + ((long)bb * 2048 + qw + lo) * 1024 + h * 64;
#pragma unroll
    for (int c = 0; c < 4; ++c)
#pragma unroll
        for (int j = 0; j < 4; ++j)
            Orow[c * 16 + g * 4 + j] = f2bf(oa[c][j] * inv);
}

// ---------------------------------------------------------------------------
// launch
// ---------------------------------------------------------------------------
extern "C" void kernel_launch(void* const* d_in, const int* in_sizes, int n_in,
                              void* d_out, int out_size, void* d_ws, size_t ws_size,
                              hipStream_t stream) {
    const float* x      = (const float*)d_in[0];
    const float* ln1_g  = (const float*)d_in[1];
    const float* ln1_b  = (const float*)d_in[2];
    const float* qkv_w  = (const float*)d_in[3];
    const float* qkv_b  = (const float*)d_in[4];
    const float* out_w  = (const float*)d_in[5];
    const float* out_b  = (const float*)d_in[6];
    const float* ln2_g  = (const float*)d_in[7];
    const float* ln2_b  = (const float*)d_in[8];
    const float* fc1_w  = (const float*)d_in[9];
    const float* fc1_b  = (const float*)d_in[10];
    const float* fc2_w  = (const float*)d_in[11];
    const float* fc2_b  = (const float*)d_in[12];
    float* out = (float*)d_out;

    const size_t MB = 1024ull * 1024ull;
    if (ws_size < 120 * MB) return;  // need 120 MB scratch
    char* ws = (char*)d_ws;
    u16* wqkv = (u16*)(ws + 0);        // 6 MB
    u16* wout = (u16*)(ws + 6 * MB);   // 2 MB
    u16* wfc1 = (u16*)(ws + 8 * MB);   // 8 MB
    u16* wfc2 = (u16*)(ws + 16 * MB);  // 8 MB
    u16* hbuf = (u16*)(ws + 24 * MB);  // 16 MB  (LN output, bf16)
    u16* obuf = (u16*)(ws + 40 * MB);  // 16 MB  (attn output, bf16)
    u16* Qb   = (u16*)(ws + 56 * MB);  // 16 MB
    u16* Kb   = (u16*)(ws + 72 * MB);  // 16 MB
    u16* Vtb  = (u16*)(ws + 88 * MB);  // 16 MB
    u16* gbuf = (u16*)(ws + 56 * MB);  // 64 MB  (FFN hidden, reuses Q/K/Vt)

    // weights -> bf16
    cvt_f32_bf16<<<3072, 256, 0, stream>>>(qkv_w, wqkv, 3072 * 1024 / 4);
    cvt_f32_bf16<<<1024, 256, 0, stream>>>(out_w, wout, 1024 * 1024 / 4);
    cvt_f32_bf16<<<4096, 256, 0, stream>>>(fc1_w, wfc1, 4096 * 1024 / 4);
    cvt_f32_bf16<<<4096, 256, 0, stream>>>(fc2_w, wfc2, 1024 * 4096 / 4);

    // LN1
    ln_bf16<<<8192, 256, 0, stream>>>(x, ln1_g, ln1_b, hbuf);
    // QKV projection -> scatter Q/K/Vt
    gemm_bt<3><<<dim3(24, 64), 256, 0, stream>>>(hbuf, wqkv, qkv_b, nullptr,
                                                 nullptr, nullptr, Qb, Kb, Vtb,
                                                 8192, 3072, 1024);
    // attention
    attn_fwd<<<dim3(64, 32), 256, 0, stream>>>(Qb, Kb, Vtb, obuf);
    // out projection + residual (res = original x) -> d_out (fp32)
    gemm_bt<2><<<dim3(8, 64), 256, 0, stream>>>(obuf, wout, out_b, x, out,
                                                nullptr, nullptr, nullptr, nullptr,
                                                8192, 1024, 1024);
    // LN2
    ln_bf16<<<8192, 256, 0, stream>>>(out, ln2_g, ln2_b, hbuf);
    // FC1 + GELU
    gemm_bt<1><<<dim3(32, 64), 256, 0, stream>>>(hbuf, wfc1, fc1_b, nullptr,
                                                 nullptr, gbuf, nullptr, nullptr,
                                                 nullptr, 8192, 4096, 1024);
    // FC2 + residual -> d_out
    gemm_bt<2><<<dim3(8, 64), 256, 0, stream>>>(gbuf, wfc2, fc2_b, out, out,
                                                nullptr, nullptr, nullptr, nullptr,
                                                8192, 1024, 4096);
}

// Round 2
// 520.781 us; speedup vs baseline: 1.2099x; 1.2099x over previous
//
#include <hip/hip_runtime.h>
#include <math.h>

// ---------------------------------------------------------------------------
// Types / helpers
// ---------------------------------------------------------------------------
using u16 = unsigned short;
typedef __attribute__((ext_vector_type(8))) short short8;   // 8 x bf16 (raw bits)
typedef __attribute__((ext_vector_type(4))) float f32x4;
typedef __attribute__((ext_vector_type(16))) float f32x16;
typedef __attribute__((ext_vector_type(4))) u16 u16x4;

#define DEV __device__ __forceinline__

DEV u16 f2bf(float f) {                       // f32 -> bf16, round-nearest-even
    unsigned u = __float_as_uint(f);
    u += 0x7fffu + ((u >> 16) & 1u);
    return (u16)(u >> 16);
}
DEV float bf2f(u16 h) { return __uint_as_float(((unsigned)h) << 16); }

DEV short8 ld16(const u16* p) { return *reinterpret_cast<const short8*>(p); }

DEV float gelu_f(float x) { return 0.5f * x * (1.f + erff(x * 0.70710678118654752f)); }

DEV unsigned pk2(float a, float b) {          // two f32 -> packed bf16x2
    return (unsigned)f2bf(a) | ((unsigned)f2bf(b) << 16);
}

// async global->LDS, 16B per lane, LDS dest = wave-uniform base + lane*16
#define GLL16(gp, lp)                                                          \
    __builtin_amdgcn_global_load_lds(                                          \
        (const __attribute__((address_space(1))) void*)(gp),                   \
        (__attribute__((address_space(3))) void*)(lp), 16, 0, 0)

// ---------------------------------------------------------------------------
// fp32 -> bf16 convert (weights)
// ---------------------------------------------------------------------------
__global__ void cvt_f32_bf16(const float* __restrict__ in, u16* __restrict__ out, int n4) {
    int i = blockIdx.x * 256 + threadIdx.x;
    if (i >= n4) return;
    float4 v = reinterpret_cast<const float4*>(in)[i];
    u16x4 o;
    o.x = f2bf(v.x); o.y = f2bf(v.y); o.z = f2bf(v.z); o.w = f2bf(v.w);
    reinterpret_cast<u16x4*>(out)[i] = o;
}

// ---------------------------------------------------------------------------
// LayerNorm (fp32 in) -> bf16 out.  One block per row, 256 threads x 4 floats.
// ---------------------------------------------------------------------------
__global__ __launch_bounds__(256) void ln_bf16(const float* __restrict__ x,
                                               const float* __restrict__ gm,
                                               const float* __restrict__ bt,
                                               u16* __restrict__ out) {
    const int row = blockIdx.x, tid = threadIdx.x;
    const float4 v = reinterpret_cast<const float4*>(x + (long)row * 1024)[tid];
    float s  = v.x + v.y + v.z + v.w;
    float sq = v.x * v.x + v.y * v.y + v.z * v.z + v.w * v.w;
#pragma unroll
    for (int off = 1; off <= 32; off <<= 1) {
        s  += __shfl_xor(s, off);
        sq += __shfl_xor(sq, off);
    }
    __shared__ float ss[4], ssq[4];
    const int wave = tid >> 6, lane = tid & 63;
    if (lane == 0) { ss[wave] = s; ssq[wave] = sq; }
    __syncthreads();
    s  = ss[0] + ss[1] + ss[2] + ss[3];
    sq = ssq[0] + ssq[1] + ssq[2] + ssq[3];
    const float mu   = s * (1.f / 1024.f);
    const float var  = sq * (1.f / 1024.f) - mu * mu;
    const float rstd = rsqrtf(var + 1e-5f);
    const float4 g4 = reinterpret_cast<const float4*>(gm)[tid];
    const float4 b4 = reinterpret_cast<const float4*>(bt)[tid];
    u16x4 o;
    o.x = f2bf((v.x - mu) * rstd * g4.x + b4.x);
    o.y = f2bf((v.y - mu) * rstd * g4.y + b4.y);
    o.z = f2bf((v.z - mu) * rstd * g4.z + b4.z);
    o.w = f2bf((v.w - mu) * rstd * g4.w + b4.w);
    reinterpret_cast<u16x4*>(out + (long)row * 1024)[tid] = o;
}

// ---------------------------------------------------------------------------
// GEMM: C[M,N] = A[M,K] @ B[N,K]^T + bias.  A,B bf16; 128x128 tile, BK=32,
// 4 waves (2x2), 4x4 16x16x32 MFMA frags per wave, global_load_lds staging.
// EPI: 0 = bf16 out, 1 = bf16 gelu out, 2 = fp32 out + residual,
//      3 = scatter into Q [BH,S,64], K [BH,S,64], Vt [BH,64,S]
// ---------------------------------------------------------------------------
template <int EPI>
__global__ __launch_bounds__(256, 2) void gemm_bt(
    const u16* __restrict__ A, const u16* __restrict__ B,
    const float* __restrict__ bias, const float* res, float* outf,
    u16* __restrict__ outb, u16* __restrict__ Qb, u16* __restrict__ Kb,
    u16* __restrict__ Vtb, int M, int N, int K) {
    __shared__ u16 As[128 * 32];
    __shared__ u16 Bs[128 * 32];
    const int tid = threadIdx.x;
    const int wave = tid >> 6, lane = tid & 63;
    const int row0 = blockIdx.y * 128, col0 = blockIdx.x * 128;
    const int wr = wave >> 1, wc = wave & 1;
    const int lo = lane & 15, g = lane >> 4;

    const u16* Ag = A + (long)(row0 + wave * 16 + (lane >> 2)) * K + (lane & 3) * 8;
    const u16* Bg = B + (long)(col0 + wave * 16 + (lane >> 2)) * K + (lane & 3) * 8;
    u16* Al = As + wave * 512;
    u16* Bl = Bs + wave * 512;

    f32x4 acc[4][4] = {};

    for (int k0 = 0; k0 < K; k0 += 32) {
        GLL16(Ag, Al);
        GLL16(Ag + 64 * (long)K, Al + 2048);
        GLL16(Bg, Bl);
        GLL16(Bg + 64 * (long)K, Bl + 2048);
        Ag += 32; Bg += 32;
        __syncthreads();
        short8 af[4], bfr[4];
#pragma unroll
        for (int m = 0; m < 4; ++m)
            af[m] = ld16(&As[(wr * 64 + m * 16 + lo) * 32 + g * 8]);
#pragma unroll
        for (int n = 0; n < 4; ++n)
            bfr[n] = ld16(&Bs[(wc * 64 + n * 16 + lo) * 32 + g * 8]);
#pragma unroll
        for (int m = 0; m < 4; ++m)
#pragma unroll
            for (int n = 0; n < 4; ++n)
                acc[m][n] = __builtin_amdgcn_mfma_f32_16x16x32_bf16(
                    af[m], bfr[n], acc[m][n], 0, 0, 0);
        __syncthreads();
    }

#pragma unroll
    for (int m = 0; m < 4; ++m) {
#pragma unroll
        for (int n = 0; n < 4; ++n) {
            const int c = col0 + wc * 64 + n * 16 + lo;
            const float bs = bias[c];
#pragma unroll
            for (int j = 0; j < 4; ++j) {
                const int r = row0 + wr * 64 + m * 16 + g * 4 + j;
                const float val = acc[m][n][j] + bs;
                if constexpr (EPI == 0) {
                    outb[(long)r * N + c] = f2bf(val);
                } else if constexpr (EPI == 1) {
                    outb[(long)r * N + c] = f2bf(gelu_f(val));
                } else if constexpr (EPI == 2) {
                    outf[(long)r * N + c] = res[(long)r * N + c] + val;
                } else {  // EPI == 3: qkv scatter
                    const int part = c >> 10, cc = c & 1023;
                    const int head = cc >> 6, d = cc & 63;
                    const int bb = r >> 11, srow = r & 2047;
                    const int bh = bb * 16 + head;
                    const u16 hv = f2bf(val);
                    if (part == 0)      Qb[((long)bh * 2048 + srow) * 64 + d] = hv;
                    else if (part == 1) Kb[((long)bh * 2048 + srow) * 64 + d] = hv;
                    else                Vtb[((long)bh * 64 + d) * 2048 + srow] = hv;
                }
            }
        }
    }
}

// ---------------------------------------------------------------------------
// Causal flash attention, 32x32x16 MFMA structure (m214-style).
// Q,K: [BH, S, 64] bf16.  Vt: [BH, 64, S] bf16.  O: [B, S, H*64] bf16.
// One wave = 32 q rows, KVBLK = 64.  S^T = K*Q^T (P columns lane-local),
// O^T = Vt*P^T.  Block = 4 waves = 128 q rows; no barriers (waves indep).
// ---------------------------------------------------------------------------
__global__ __launch_bounds__(256) void attn_fwd32(
    const u16* __restrict__ Q, const u16* __restrict__ K,
    const u16* __restrict__ Vt, u16* __restrict__ O) {
    const int bh = blockIdx.x;
    const int qt = 15 - blockIdx.y;          // heavy q-tiles dispatch first
    const int wave = threadIdx.x >> 6, lane = threadIdx.x & 63;
    const int lq = lane & 31, hi = lane >> 5;
    const int qw = qt * 128 + wave * 32;

    const u16* Qp = Q + ((long)bh * 2048 + qw) * 64;
    const u16* Kp = K + (long)bh * 2048 * 64;
    const u16* Vp = Vt + (long)bh * 64 * 2048;

    // Q^T B-frags: lane holds Q[qw+lq][ks*16 + hi*8 + jj]
    short8 qf[4];
#pragma unroll
    for (int ks = 0; ks < 4; ++ks)
        qf[ks] = ld16(Qp + lq * 64 + ks * 16 + hi * 8);

    f32x16 o0 = {}, o1 = {};
    float m = -1e30f, l = 0.f;
    const float scale = 0.125f;              // 1/sqrt(64)
    const int q_abs = qw + lq;
    const int nkv = qw + 32;

    for (int kv0 = 0; kv0 < nkv; kv0 += 64) {
        // ---- S^T = K * Q^T  (two 32-kv tiles) ----
        f32x16 s0 = {}, s1 = {};
        const u16* Kr = Kp + (long)(kv0 + lq) * 64 + hi * 8;
#pragma unroll
        for (int ks = 0; ks < 4; ++ks)
            s0 = __builtin_amdgcn_mfma_f32_32x32x16_bf16(
                ld16(Kr + ks * 16), qf[ks], s0, 0, 0, 0);
        const u16* Kr2 = Kr + 32 * 64;
#pragma unroll
        for (int ks = 0; ks < 4; ++ks)
            s1 = __builtin_amdgcn_mfma_f32_32x32x16_bf16(
                ld16(Kr2 + ks * 16), qf[ks], s1, 0, 0, 0);

        // ---- scale (+ causal mask on the unique diagonal iteration) ----
        float mt = -1e30f;
        if (kv0 + 64 >= nkv) {               // diagonal tile
#pragma unroll
            for (int r = 0; r < 16; ++r) {
                const int kv = kv0 + (r & 3) + 8 * (r >> 2) + 4 * hi;
                float v = s0[r] * scale;
                if (kv > q_abs) v = -1e30f;
                s0[r] = v; mt = fmaxf(mt, v);
                v = s1[r] * scale;
                if (kv + 32 > q_abs) v = -1e30f;
                s1[r] = v; mt = fmaxf(mt, v);
            }
        } else {
#pragma unroll
            for (int r = 0; r < 16; ++r) {
                s0[r] *= scale; s1[r] *= scale;
                mt = fmaxf(mt, fmaxf(s0[r], s1[r]));
            }
        }
        mt = fmaxf(mt, __shfl_xor(mt, 32));  // combine lane pair (hi split)

        const float mn = fmaxf(m, mt);
        const float corr = __expf(m - mn);
        m = mn;
        float ps = 0.f;
#pragma unroll
        for (int r = 0; r < 16; ++r) {
            s0[r] = __expf(s0[r] - mn); ps += s0[r];
            s1[r] = __expf(s1[r] - mn); ps += s1[r];
        }
        l = l * corr + ps;
        o0 *= corr; o1 *= corr;

        // ---- build P^T B-frags (4 chunks of kv16), 2 shuffles each ----
        short8 pf[4];
#pragma unroll
        for (int c = 0; c < 4; ++c) {
            const f32x16& src = (c >> 1) ? s1 : s0;
            const int b = (c & 1) * 8;
            const unsigned A0 = pk2(src[b + 0], src[b + 1]);
            const unsigned A1 = pk2(src[b + 2], src[b + 3]);
            const unsigned B0 = pk2(src[b + 4], src[b + 5]);
            const unsigned B1 = pk2(src[b + 6], src[b + 7]);
            const unsigned S0 = hi ? A0 : B0;
            const unsigned S1 = hi ? A1 : B1;
            const unsigned R0 = (unsigned)__shfl_xor((int)S0, 32);
            const unsigned R1 = (unsigned)__shfl_xor((int)S1, 32);
            union { unsigned u[4]; short8 v; } fr;
            fr.u[0] = hi ? R0 : A0;
            fr.u[1] = hi ? R1 : A1;
            fr.u[2] = hi ? B0 : R0;
            fr.u[3] = hi ? B1 : R1;
            pf[c] = fr.v;
        }

        // ---- O^T += Vt * P^T ----
        const u16* Vr = Vp + (long)lq * 2048 + kv0 + hi * 8;
#pragma unroll
        for (int c = 0; c < 4; ++c) {
            o0 = __builtin_amdgcn_mfma_f32_32x32x16_bf16(
                ld16(Vr + c * 16), pf[c], o0, 0, 0, 0);
            o1 = __builtin_amdgcn_mfma_f32_32x32x16_bf16(
                ld16(Vr + 32 * 2048 + c * 16), pf[c], o1, 0, 0, 0);
        }
    }

    // ---- finish: combine l across lane pair, normalize, store ----
    l += __shfl_xor(l, 32);
    const float inv = 1.f / l;
    const int bb = bh >> 4, h = bh & 15;
    u16* Orow = O + ((long)(bb * 2048 + qw + lq)) * 1024 + h * 64;
#pragma unroll
    for (int k4 = 0; k4 < 4; ++k4) {
        u16x4 w0, w1;
#pragma unroll
        for (int j = 0; j < 4; ++j) {
            w0[j] = f2bf(o0[k4 * 4 + j] * inv);   // d = 8*k4 + 4*hi + j
            w1[j] = f2bf(o1[k4 * 4 + j] * inv);   // d = 32 + 8*k4 + 4*hi + j
        }
        *reinterpret_cast<u16x4*>(Orow + 8 * k4 + 4 * hi)      = w0;
        *reinterpret_cast<u16x4*>(Orow + 32 + 8 * k4 + 4 * hi) = w1;
    }
}

// ---------------------------------------------------------------------------
// launch
// ---------------------------------------------------------------------------
extern "C" void kernel_launch(void* const* d_in, const int* in_sizes, int n_in,
                              void* d_out, int out_size, void* d_ws, size_t ws_size,
                              hipStream_t stream) {
    const float* x      = (const float*)d_in[0];
    const float* ln1_g  = (const float*)d_in[1];
    const float* ln1_b  = (const float*)d_in[2];
    const float* qkv_w  = (const float*)d_in[3];
    const float* qkv_b  = (const float*)d_in[4];
    const float* out_w  = (const float*)d_in[5];
    const float* out_b  = (const float*)d_in[6];
    const float* ln2_g  = (const float*)d_in[7];
    const float* ln2_b  = (const float*)d_in[8];
    const float* fc1_w  = (const float*)d_in[9];
    const float* fc1_b  = (const float*)d_in[10];
    const float* fc2_w  = (const float*)d_in[11];
    const float* fc2_b  = (const float*)d_in[12];
    float* out = (float*)d_out;

    const size_t MB = 1024ull * 1024ull;
    if (ws_size < 120 * MB) return;
    char* ws = (char*)d_ws;
    u16* wqkv = (u16*)(ws + 0);        // 6 MB
    u16* wout = (u16*)(ws + 6 * MB);   // 2 MB
    u16* wfc1 = (u16*)(ws + 8 * MB);   // 8 MB
    u16* wfc2 = (u16*)(ws + 16 * MB);  // 8 MB
    u16* hbuf = (u16*)(ws + 24 * MB);  // 16 MB  (LN output, bf16)
    u16* obuf = (u16*)(ws + 40 * MB);  // 16 MB  (attn output, bf16)
    u16* Qb   = (u16*)(ws + 56 * MB);  // 16 MB
    u16* Kb   = (u16*)(ws + 72 * MB);  // 16 MB
    u16* Vtb  = (u16*)(ws + 88 * MB);  // 16 MB
    u16* gbuf = (u16*)(ws + 56 * MB);  // 64 MB  (FFN hidden, reuses Q/K/Vt)

    cvt_f32_bf16<<<3072, 256, 0, stream>>>(qkv_w, wqkv, 3072 * 1024 / 4);
    cvt_f32_bf16<<<1024, 256, 0, stream>>>(out_w, wout, 1024 * 1024 / 4);
    cvt_f32_bf16<<<4096, 256, 0, stream>>>(fc1_w, wfc1, 4096 * 1024 / 4);
    cvt_f32_bf16<<<4096, 256, 0, stream>>>(fc2_w, wfc2, 1024 * 4096 / 4);

    ln_bf16<<<8192, 256, 0, stream>>>(x, ln1_g, ln1_b, hbuf);
    gemm_bt<3><<<dim3(24, 64), 256, 0, stream>>>(hbuf, wqkv, qkv_b, nullptr,
                                                 nullptr, nullptr, Qb, Kb, Vtb,
                                                 8192, 3072, 1024);
    attn_fwd32<<<dim3(64, 16), 256, 0, stream>>>(Qb, Kb, Vtb, obuf);
    gemm_bt<2><<<dim3(8, 64), 256, 0, stream>>>(obuf, wout, out_b, x, out,
                                                nullptr, nullptr, nullptr, nullptr,
                                                8192, 1024, 1024);
    ln_bf16<<<8192, 256, 0, stream>>>(out, ln2_g, ln2_b, hbuf);
    gemm_bt<1><<<dim3(32, 64), 256, 0, stream>>>(hbuf, wfc1, fc1_b, nullptr,
                                                 nullptr, gbuf, nullptr, nullptr,
                                                 nullptr, 8192, 4096, 1024);
    gemm_bt<2><<<dim3(8, 64), 256, 0, stream>>>(gbuf, wfc2, fc2_b, out, out,
                                                nullptr, nullptr, nullptr, nullptr,
                                                8192, 1024, 4096);
}